// Round 2
// baseline (269.626 us; speedup 1.0000x reference)
//
#include <hip/hip_runtime.h>

// VQ-VAE quantizer — round 11: kill zv rematerialization, pin zv in arch VGPRs.
// Inputs fp32: z_e [32,64,64,64], codebook [512,64].
// Output fp32: z_q [8388608] ++ indices-as-float [131072].
//
// Reference (np, fp32): d = rn( rn(s1 + s2[k]) - 2*M32[k] ), argmin ties->lowest.
//   s1 = np.sum(z**2,axis=1):  square->round, pairwise-8 accumulators, no fma.
//   s2 = np.sum(cb**2,axis=1): same.
//   M32 = sgemm(z_flat, cb^T): sequential-k fmaf chain (OpenBLAS microkernel).
// The fp32 grid must be replicated EXACTLY (R8). R11 changes NO arithmetic.
//
// R10 post-mortem: 4-way ILP was neutral (207us, VGPR_Count still 44,
// VALUBusy still 62%). 44 VGPRs cannot hold zv[64], and the allocator had a
// 2-waves/EU budget -> not pressure. Conclusion: regalloc REMATERIALIZES zv
// by re-loading z from global inside the k-loop (cost model says cache-hit
// loads < 64 live regs). That is 4.3 GB of L1/L2 re-read traffic per pass
// (~125us at L2 BW) -> the kernel is L2-bound, which is why ILP didn't help.
//
// Fix: launder zv through an empty inline asm with "+v" constraints after the
// load. The values become asm-defined -> remat from memory is impossible, and
// constraint class "v" pins them to arch VGPRs. A second (zero-instruction)
// asm inside the k-loop forces residency across every iteration. Inner loop
// should become pure v_fmac_f32 v, s(codebook), v(zv).

typedef __attribute__((ext_vector_type(4))) float fl4;

#define PIN_ZQ() asm volatile("" \
    : "+v"(zq[0]), "+v"(zq[1]), "+v"(zq[2]),  "+v"(zq[3]), \
      "+v"(zq[4]), "+v"(zq[5]), "+v"(zq[6]),  "+v"(zq[7]), \
      "+v"(zq[8]), "+v"(zq[9]), "+v"(zq[10]), "+v"(zq[11]), \
      "+v"(zq[12]),"+v"(zq[13]),"+v"(zq[14]), "+v"(zq[15]))

__global__ __launch_bounds__(256, 2)
void vq11(const float* __restrict__ z,
          const float* __restrict__ cb,
          float* __restrict__ out)
{
    __shared__ float s2l[512];
    __shared__ int   ifin[256];

    const int tid = threadIdx.x;
    const int n0  = blockIdx.x << 8;     // 512 blocks x 256 samples
    const int n   = n0 + tid;

    // ---- s2[k] = np.sum(cb[k]**2): square->round->add, pairwise-8, no fma ----
    for (int k = tid; k < 512; k += 256) {
        const float* row = cb + k * 64;
        float p[8];
        #pragma unroll
        for (int j = 0; j < 8; ++j) p[j] = __fmul_rn(row[j], row[j]);
        #pragma unroll
        for (int m = 1; m < 8; ++m)
            #pragma unroll
            for (int j = 0; j < 8; ++j)
                p[j] = __fadd_rn(p[j], __fmul_rn(row[m * 8 + j], row[m * 8 + j]));
        s2l[k] = __fadd_rn(__fadd_rn(__fadd_rn(p[0], p[1]), __fadd_rn(p[2], p[3])),
                           __fadd_rn(__fadd_rn(p[4], p[5]), __fadd_rn(p[6], p[7])));
    }
    __syncthreads();

    // ---- load sample n (coalesced: fixed c => consecutive tid, consecutive addr) ----
    // channel c of sample n: z[(n>>12)*262144 + c*4096 + (n&4095)]
    const size_t base = (size_t)(n >> 12) * 262144 + (size_t)(n & 4095);
    fl4  zq[16];                               // 64 floats, SROA -> 16 vec regs
    float p[8];
    #pragma unroll
    for (int c = 0; c < 64; ++c) {
        const float v = z[base + (size_t)c * 4096];
        zq[c >> 2][c & 3] = v;
        const float sq = __fmul_rn(v, v);          // np: z**2 rounds first
        if (c < 8) p[c] = sq;                      // m = 0
        else       p[c & 7] = __fadd_rn(p[c & 7], sq);   // m ascending per j: np order
    }
    const float s1 = __fadd_rn(__fadd_rn(__fadd_rn(p[0], p[1]), __fadd_rn(p[2], p[3])),
                               __fadd_rn(__fadd_rn(p[4], p[5]), __fadd_rn(p[6], p[7])));

    // Launder: zq now asm-defined -> no remat from global; class "v" = arch VGPR.
    PIN_ZQ();

    // ---- argmin on the reference's fp32 grid — 4 k-chains in flight ----
    // Each m_i is a single-accumulator, c-ascending fmaf chain: bit-identical
    // to the reference BLAS microkernel per (n,k).
    float best = 3.4e38f;
    int   bi   = 0;
    for (int k0 = 0; k0 < 512; k0 += 4) {
        PIN_ZQ();                                  // zero-instruction residency fence
        const float* __restrict__ r0 = cb + (size_t)(k0 + 0) * 64;  // wave-uniform
        const float* __restrict__ r1 = cb + (size_t)(k0 + 1) * 64;  //  -> s_load
        const float* __restrict__ r2 = cb + (size_t)(k0 + 2) * 64;
        const float* __restrict__ r3 = cb + (size_t)(k0 + 3) * 64;
        float m0 = 0.0f, m1 = 0.0f, m2 = 0.0f, m3 = 0.0f;
        #pragma unroll
        for (int c = 0; c < 64; ++c) {
            const float zc = zq[c >> 2][c & 3];
            m0 = fmaf(r0[c], zc, m0);
            m1 = fmaf(r1[c], zc, m1);
            m2 = fmaf(r2[c], zc, m2);
            m3 = fmaf(r3[c], zc, m3);
        }
        // ascending k, strict <: lowest index wins ties (same as R9/R10)
        float T, d;
        T = __fadd_rn(s1, s2l[k0 + 0]); d = __fsub_rn(T, 2.0f * m0);
        if (d < best) { best = d; bi = k0 + 0; }
        T = __fadd_rn(s1, s2l[k0 + 1]); d = __fsub_rn(T, 2.0f * m1);
        if (d < best) { best = d; bi = k0 + 1; }
        T = __fadd_rn(s1, s2l[k0 + 2]); d = __fsub_rn(T, 2.0f * m2);
        if (d < best) { best = d; bi = k0 + 2; }
        T = __fadd_rn(s1, s2l[k0 + 3]); d = __fsub_rn(T, 2.0f * m3);
        if (d < best) { best = d; bi = k0 + 3; }
    }
    ifin[tid] = bi;
    out[8388608 + n] = (float)bi;                  // index as fp32 (exact)
    __syncthreads();

    // ---- z_q gather: exact fp32 copies, coalesced 16B stores (R8: passed) ----
    float* ob = out + (size_t)n0 * 64;
    #pragma unroll
    for (int it = 0; it < 16; ++it) {
        const int o    = it * 1024 + tid * 4;   // float offset in chunk [0, 16384)
        const int sloc = o >> 6;                // local sample
        const int c0   = o & 63;                // channel start (multiple of 4)
        const int idx  = ifin[sloc] & 511;      // defensive clamp
        const fl4 v = *(const fl4*)(cb + idx * 64 + c0);
        *(fl4*)(ob + o) = v;
    }
}

extern "C" void kernel_launch(void* const* d_in, const int* in_sizes, int n_in,
                              void* d_out, int out_size, void* d_ws, size_t ws_size,
                              hipStream_t stream) {
    const float* z  = (const float*)d_in[0];   // z_e fp32 [32,64,64,64]
    const float* cb = (const float*)d_in[1];   // codebook fp32 [512,64]
    float* out = (float*)d_out;                // fp32: z_q [8388608] ++ indices [131072]
    vq11<<<512, 256, 0, stream>>>(z, cb, out);
}

// Round 3
// 258.254 us; speedup vs baseline: 1.0440x; 1.0440x over previous
//
#include <hip/hip_runtime.h>

// VQ-VAE quantizer — round 12: z lives in LDS (transposed), not registers.
// Inputs fp32: z_e [32,64,64,64], codebook [512,64].
// Output fp32: z_q [8388608] ++ indices-as-float [131072].
//
// Reference (np, fp32): d = rn( rn(s1 + s2[k]) - 2*M32[k] ), argmin ties->lowest.
//   s1 = np.sum(z**2,axis=1):  square->round, pairwise-8 accumulators, no fma.
//   s2 = np.sum(cb**2,axis=1): same.
//   M32 = sgemm(z_flat, cb^T): sequential-k fmaf chain (OpenBLAS microkernel).
// The fp32 grid must be replicated EXACTLY (R8). R12 changes NO arithmetic.
//
// R10/R11 post-mortem: VGPR_Count 40-44 with a 256-reg budget => the unified-
// file allocator keeps zv[64] in AGPRs (cheap-spill class) and pays a
// v_accvgpr_read (VALU, 2cyc) per use inside the k-loop. VALU-busy 138us ~=
// fma issue (55us) + accvgpr reads (~55-80us). Neither ILP (R10) nor asm
// boundary pins (R11) can stop mid-loop eviction. Fix is structural: park the
// per-thread z column in LDS, TRANSPOSED (zl[c][tid]):
//   * lane l reads zl[c][l]: consecutive lanes -> consecutive banks; worst
//     case lane l vs l+32 = 2-way aliasing = free (learn_hip m136). No pad.
//   * one address VGPR (tid*4); all 64 reads use the 16-bit offset: immediate
//     (c*1024 <= 64512) -> zero per-read address VALU.
//   * each ds_read_b32 feeds 4 fmas -> LDS pipe (~371 cyc/iter) hides under
//     VALU (512 cyc/iter).
//   * zl is written and read by the SAME thread -> no barrier needed.
// LDS: 64KB zl + 2KB s2l + 1KB ifin = 67KB/block; 2 blocks/CU = 134 <= 160KB.

typedef __attribute__((ext_vector_type(4))) float fl4;

__global__ __launch_bounds__(256, 2)
void vq12(const float* __restrict__ z,
          const float* __restrict__ cb,
          float* __restrict__ out)
{
    __shared__ float zl[64][256];    // transposed: zl[c][tid]
    __shared__ float s2l[512];
    __shared__ int   ifin[256];

    const int tid = threadIdx.x;
    const int n0  = blockIdx.x << 8;     // 512 blocks x 256 samples
    const int n   = n0 + tid;

    // ---- s2[k] = np.sum(cb[k]**2): square->round->add, pairwise-8, no fma ----
    for (int k = tid; k < 512; k += 256) {
        const float* row = cb + k * 64;
        float p[8];
        #pragma unroll
        for (int j = 0; j < 8; ++j) p[j] = __fmul_rn(row[j], row[j]);
        #pragma unroll
        for (int m = 1; m < 8; ++m)
            #pragma unroll
            for (int j = 0; j < 8; ++j)
                p[j] = __fadd_rn(p[j], __fmul_rn(row[m * 8 + j], row[m * 8 + j]));
        s2l[k] = __fadd_rn(__fadd_rn(__fadd_rn(p[0], p[1]), __fadd_rn(p[2], p[3])),
                           __fadd_rn(__fadd_rn(p[4], p[5]), __fadd_rn(p[6], p[7])));
    }
    __syncthreads();

    // ---- load sample n (coalesced), compute s1, stage z into zl[c][tid] ----
    // channel c of sample n: z[(n>>12)*262144 + c*4096 + (n&4095)]
    const size_t base = (size_t)(n >> 12) * 262144 + (size_t)(n & 4095);
    float p[8];
    #pragma unroll
    for (int c = 0; c < 64; ++c) {
        const float v = z[base + (size_t)c * 4096];
        zl[c][tid] = v;                            // private column, no barrier
        const float sq = __fmul_rn(v, v);          // np: z**2 rounds first
        if (c < 8) p[c] = sq;                      // m = 0
        else       p[c & 7] = __fadd_rn(p[c & 7], sq);   // m ascending per j: np order
    }
    const float s1 = __fadd_rn(__fadd_rn(__fadd_rn(p[0], p[1]), __fadd_rn(p[2], p[3])),
                               __fadd_rn(__fadd_rn(p[4], p[5]), __fadd_rn(p[6], p[7])));

    const float* zcol = &zl[0][tid];               // byte stride 1024 per c

    // ---- argmin on the reference's fp32 grid — 4 k-chains, zc from LDS ----
    // Each m_i is a single-accumulator, c-ascending fmaf chain: bit-identical
    // to the reference BLAS microkernel per (n,k).
    float best = 3.4e38f;
    int   bi   = 0;
    for (int k0 = 0; k0 < 512; k0 += 4) {
        const float* __restrict__ r0 = cb + (size_t)(k0 + 0) * 64;  // wave-uniform
        const float* __restrict__ r1 = cb + (size_t)(k0 + 1) * 64;  //  -> s_load
        const float* __restrict__ r2 = cb + (size_t)(k0 + 2) * 64;
        const float* __restrict__ r3 = cb + (size_t)(k0 + 3) * 64;
        float m0 = 0.0f, m1 = 0.0f, m2 = 0.0f, m3 = 0.0f;
        #pragma unroll
        for (int c = 0; c < 64; ++c) {
            const float zc = zcol[c << 8];         // ds_read_b32, offset:c*1024
            m0 = fmaf(r0[c], zc, m0);
            m1 = fmaf(r1[c], zc, m1);
            m2 = fmaf(r2[c], zc, m2);
            m3 = fmaf(r3[c], zc, m3);
        }
        // ascending k, strict <: lowest index wins ties (same as R9-R11)
        float T, d;
        T = __fadd_rn(s1, s2l[k0 + 0]); d = __fsub_rn(T, 2.0f * m0);
        if (d < best) { best = d; bi = k0 + 0; }
        T = __fadd_rn(s1, s2l[k0 + 1]); d = __fsub_rn(T, 2.0f * m1);
        if (d < best) { best = d; bi = k0 + 1; }
        T = __fadd_rn(s1, s2l[k0 + 2]); d = __fsub_rn(T, 2.0f * m2);
        if (d < best) { best = d; bi = k0 + 2; }
        T = __fadd_rn(s1, s2l[k0 + 3]); d = __fsub_rn(T, 2.0f * m3);
        if (d < best) { best = d; bi = k0 + 3; }
    }
    ifin[tid] = bi;
    out[8388608 + n] = (float)bi;                  // index as fp32 (exact)
    __syncthreads();

    // ---- z_q gather: exact fp32 copies, coalesced 16B stores (R8: passed) ----
    float* ob = out + (size_t)n0 * 64;
    #pragma unroll
    for (int it = 0; it < 16; ++it) {
        const int o    = it * 1024 + tid * 4;   // float offset in chunk [0, 16384)
        const int sloc = o >> 6;                // local sample
        const int c0   = o & 63;                // channel start (multiple of 4)
        const int idx  = ifin[sloc] & 511;      // defensive clamp
        const fl4 v = *(const fl4*)(cb + idx * 64 + c0);
        *(fl4*)(ob + o) = v;
    }
}

extern "C" void kernel_launch(void* const* d_in, const int* in_sizes, int n_in,
                              void* d_out, int out_size, void* d_ws, size_t ws_size,
                              hipStream_t stream) {
    const float* z  = (const float*)d_in[0];   // z_e fp32 [32,64,64,64]
    const float* cb = (const float*)d_in[1];   // codebook fp32 [512,64]
    float* out = (float*)d_out;                // fp32: z_q [8388608] ++ indices [131072]
    vq12<<<512, 256, 0, stream>>>(z, cb, out);
}